// Round 16
// baseline (405.880 us; speedup 1.0000x reference)
//
#include <hip/hip_runtime.h>
#include <stdint.h>

// ---------------- problem constants (from reference) ----------------
#define DIN   4096
#define DOUT  4096
#define RANK  16
#define MTOT  8192            // 4 * 2048
#define LSCALE 2.0f           // alpha/rank = 32/16

typedef unsigned short u16;
typedef __bf16 bf16x8 __attribute__((ext_vector_type(8)));
typedef float  f32x4  __attribute__((ext_vector_type(4)));
typedef u16    u16x8  __attribute__((ext_vector_type(8)));

__device__ __forceinline__ u16 f2bf(float f) {
    uint32_t u = __builtin_bit_cast(uint32_t, f);
    u = (u + 0x7FFFu + ((u >> 16) & 1u)) >> 16;   // RNE
    return (u16)u;
}

__device__ __forceinline__ u16x8 pack8(f32x4 a, f32x4 b) {
    u16x8 o;
    o[0] = f2bf(a[0]); o[1] = f2bf(a[1]); o[2] = f2bf(a[2]); o[3] = f2bf(a[3]);
    o[4] = f2bf(b[0]); o[5] = f2bf(b[1]); o[6] = f2bf(b[2]); o[7] = f2bf(b[3]);
    return o;
}

#define GLDS16(g, l) __builtin_amdgcn_global_load_lds( \
    (const __attribute__((address_space(1))) void*)(g), \
    (__attribute__((address_space(3))) void*)(l), 16, 0, 0)

// ---------------- pass 1a: x (f32) -> xb (bf16) ----------------
__global__ __launch_bounds__(256) void k_convert_x(const float* __restrict__ x,
                                                   u16* __restrict__ xb) {
    long i = ((long)blockIdx.x * 256 + threadIdx.x) * 8;
    f32x4 a = *(const f32x4*)(x + i);
    f32x4 b = *(const f32x4*)(x + i + 4);
    *(u16x8*)(xb + i) = pack8(a, b);
}

// ---------------- pass 1b: W_eff = W + scale * B @ A  (bf16) ----------------
// Thread owns one d-chunk (8 f32) and 16 consecutive o rows; A-chunks hoisted
// to registers once (A L2 traffic 1GB -> 64MB).  [r12: at memory floor]
#define WEFF_OPG 16
__global__ __launch_bounds__(256) void k_build_weff(const float* __restrict__ W,
                                                    const float* __restrict__ A,
                                                    const float* __restrict__ B,
                                                    u16* __restrict__ wb) {
    const long t = (long)blockIdx.x * 256 + threadIdx.x;   // 512 dchunks x 256 ogroups
    const int dc = (int)(t & 511);
    const int og = (int)(t >> 9);
    const int d  = dc * 8;
    f32x4 a0[RANK], a1[RANK];
#pragma unroll
    for (int r = 0; r < RANK; ++r) {
        a0[r] = *(const f32x4*)(A + (long)r * DIN + d);
        a1[r] = *(const f32x4*)(A + (long)r * DIN + d + 4);
    }
#pragma unroll 4
    for (int j = 0; j < WEFF_OPG; ++j) {
        const int o = og * WEFF_OPG + j;
        const long i = (long)o * DIN + d;
        f32x4 w0 = *(const f32x4*)(W + i);
        f32x4 w1 = *(const f32x4*)(W + i + 4);
#pragma unroll
        for (int r = 0; r < RANK; ++r) {
            const float s = B[o * RANK + r] * LSCALE;
            w0 += a0[r] * s;
            w1 += a1[r] * s;
        }
        *(u16x8*)(wb + i) = pack8(w0, w1);
    }
}

// ---------------- main GEMM: out = xb @ wb^T + bias ----------------
// LDS-TRAFFIC REDUCTION: 256x256 tile, BK=64, FOUR waves (2Mx2N), wave tile
// 128x128 (acc[8][8] f32x4 = 256 VGPR -> 1 wave/SIMD, ~370 VGPR total, no
// spill expected under the 450 threshold). LDS reads/tile drop 196->131 KB
// (wave B/FLOP (128+128)/(128*128) vs (128+64)/(128*64) = -33%) — attacks
// the measured LDS-read-pipe bound (4560 cyc/tile ~= LDS service time).
// r12 2-phase skeleton, 2 barriers + 1 counted gate per K-tile:
//   Ph1: stage A(t+1)->nxt (8); read afL(8)+bfHi(8); Q(m0-3 x all-n); BAR
//   Ph2: stage B(t+2)->cur (8); GATE vmcnt(8); read afH(8)+bLo(t+1)(8);
//        Q(m4-7 x all-n); BAR
// FIFO at Ph2 gate: B(t+1)[8] + A(t+1)[8] + B(t+2)[8] = 24 outstanding ->
// vmcnt(8) retires B(t+1)+A(t+1) (own portions deterministic; cross-wave
// B margin ~1 tile as in r12), keeps B(t+2) in flight. Never 0 in loop.
#define BM 256
#define BN 256
#define BK 64
#define NT (DIN / BK)          // 64 K-tiles

#define MFMA16(d, a, b) d = __builtin_amdgcn_mfma_f32_16x16x32_bf16(a, b, d, 0, 0, 0)
#define ABAR()   asm volatile("s_barrier" ::: "memory")
#define GATE8()  asm volatile("s_waitcnt vmcnt(8)" ::: "memory")
#define PRIO1()  __builtin_amdgcn_s_setprio(1)
#define PRIO0()  __builtin_amdgcn_s_setprio(0)

// 32 MFMAs, kk-outer (16 independent accs between dependent reuses)
#define QUADK(mo, no, AF, BF) \
    _Pragma("unroll") \
    for (int kk = 0; kk < 2; ++kk) { \
        _Pragma("unroll") \
        for (int m = 0; m < 4; ++m) { \
            _Pragma("unroll") \
            for (int n = 0; n < 4; ++n) { \
                MFMA16(acc[(mo)+m][(no)+n], AF[m][kk], BF[n][kk]); \
            } \
        } \
    }

__global__ __launch_bounds__(256, 1) void k_gemm_ws(const u16* __restrict__ xb,
                                                    const u16* __restrict__ wb,
                                                    const float* __restrict__ bias,
                                                    float* __restrict__ out) {
    constexpr int K = DIN, N = DOUT;
    __shared__ alignas(16) u16 lds[65536];   // A0@0 A1@16384 B0@32768 B1@49152 (u16)

    // T1: bijective XCD swizzle (gridDim.x = 512, divisible by 8)
    const int nchunk = gridDim.x >> 3;
    const int bid = blockIdx.x;
    const int wg  = (bid & 7) * nchunk + (bid >> 3);
    const int bm  = (wg & 31) * BM;
    const int bn  = (wg >> 5) * BN;

    const int tid  = threadIdx.x;              // 0..255
    const int lane = tid & 63;
    const int wid  = tid >> 6;                 // 0..3
    const int wr   = wid >> 1;                 // 0..1 -> rows wr*128..+127
    const int wc   = wid & 1;                  // 0..1 -> cols wc*128..+127
    const int lrow = lane & 15;
    const int kgrp = lane >> 4;                // 0..3

    // ---- staging geometry (pre-swizzled global source, linear LDS dest) ----
    const int srow = tid >> 3;                 // 0..31
    const int sgl  = (tid & 7) ^ (srow & 7);
    const u16* const aSrcB = xb + (long)(bm + srow) * K + sgl * 8;
    const u16* const bSrcB = wb + (long)(bn + srow) * K + sgl * 8;

    // chunk c = tile rows 32c..32c+31 (c = 0..7)
#define STAGE_A(c, buf, kt) GLDS16(aSrcB + (long)(32*(c))*K + (kt)*BK, \
                                   lds + (buf)*16384 + (c)*2048 + tid*8)
#define STAGE_B(c, buf, kt) GLDS16(bSrcB + (long)(32*(c))*K + (kt)*BK, \
                                   lds + 32768 + (buf)*16384 + (c)*2048 + tid*8)

    // ---- fragment-read geometry (swizzled) ----
    const int go0 = (kgrp ^ (lrow & 7)) * 8;   // kk=0 granule (u16 units)
    const int go1 = go0 ^ 32;                  // kk=1 (granule ^ 4)
    const int arow = (wr*128 + lrow) * 64;     // wave A base row offset
    const int brow = (wc*128 + lrow) * 64;     // wave B base row offset

    const u16* const cA0 = lds +         arow;
    const u16* const cA1 = lds + 16384 + arow;
    const u16* const cB0 = lds + 32768 +         brow;
    const u16* const cB1 = lds + 32768 + 16384 + brow;

    f32x4 acc[8][8];
#pragma unroll
    for (int m = 0; m < 8; ++m)
#pragma unroll
        for (int n = 0; n < 8; ++n) acc[m][n] = (f32x4){0.f, 0.f, 0.f, 0.f};

    bf16x8 afL[4][2], afH[4][2], bfHi[4][2], bLoE[4][2], bLoO[4][2];

#define READ_F4(DST, BASE, OFS) \
    _Pragma("unroll") \
    for (int f = 0; f < 4; ++f) { \
        const u16* b_ = (BASE) + ((OFS) + f) * 1024; \
        DST[f][0] = *(const bf16x8*)(b_ + go0); \
        DST[f][1] = *(const bf16x8*)(b_ + go1); \
    }

    // ---- prologue: A(0)->A0, B(0)->B0, B(1)->B1; gate; read bLo(0) ----
#pragma unroll
    for (int c = 0; c < 8; ++c) STAGE_A(c, 0, 0);
#pragma unroll
    for (int c = 0; c < 8; ++c) STAGE_B(c, 0, 0);
#pragma unroll
    for (int c = 0; c < 8; ++c) STAGE_B(c, 1, 1);
    GATE8();                       // retires A(0)+B(0); keeps B(1) in flight
    __syncthreads();
    READ_F4(bLoE, cB0, 0);

    for (int it = 0; it < NT/2; ++it) {
        const int kt1 = 2*it + 1;              // <= 63
        const int kt2 = (2*it + 2) & (NT - 1); // wraps on last iter (unused)
        const int kt3 = (2*it + 3) & (NT - 1);

        // ========== even tile t=2it (A buf0, B buf0, bLo=bLoE) ==========
        // Ph1: stage A(t+1)->A1; read afL + bfHi; Q(m0-3 x n0-7)
#pragma unroll
        for (int c = 0; c < 8; ++c) STAGE_A(c, 1, kt1);
        READ_F4(afL, cA0, 0);
        READ_F4(bfHi, cB0, 4);
        PRIO1(); QUADK(0, 0, afL, bLoE); QUADK(0, 4, afL, bfHi); PRIO0();
        ABAR();
        // Ph2: stage B(t+2)->B0; GATE; read afH + bLo(t+1); Q(m4-7 x n0-7)
#pragma unroll
        for (int c = 0; c < 8; ++c) STAGE_B(c, 0, kt2);
        GATE8();                               // retires A(t+1)+B(t+1)
        READ_F4(afH, cA0, 4);
        READ_F4(bLoO, cB1, 0);
        PRIO1(); QUADK(4, 0, afH, bLoE); QUADK(4, 4, afH, bfHi); PRIO0();
        ABAR();

        // ========== odd tile t+1 (A buf1, B buf1, bLo=bLoO) ==========
#pragma unroll
        for (int c = 0; c < 8; ++c) STAGE_A(c, 0, kt2);
        READ_F4(afL, cA1, 0);
        READ_F4(bfHi, cB1, 4);
        PRIO1(); QUADK(0, 0, afL, bLoO); QUADK(0, 4, afL, bfHi); PRIO0();
        ABAR();

#pragma unroll
        for (int c = 0; c < 8; ++c) STAGE_B(c, 1, kt3);
        GATE8();                               // retires A(t+2)+B(t+2)
        READ_F4(afH, cA1, 4);
        READ_F4(bLoE, cB0, 0);
        PRIO1(); QUADK(4, 0, afH, bLoO); QUADK(4, 4, afH, bfHi); PRIO0();
        ABAR();
    }
    asm volatile("s_waitcnt vmcnt(0)" ::: "memory");   // drain wrapped prefetch

    // ---- epilogue: + bias, store f32 ----
    const int orow = bm + wr*128 + kgrp*4;
    const int ocol = bn + wc*128 + lrow;
#pragma unroll
    for (int n = 0; n < 8; ++n) {
        const int col = ocol + n*16;
        const float bj = bias[col];
#pragma unroll
        for (int m = 0; m < 8; ++m) {
            const int row = orow + m*16;
#pragma unroll
            for (int r = 0; r < 4; ++r)
                out[(long)(row + r) * N + col] = acc[m][n][r] + bj;
        }
    }
}

// ---------------- fallback: T = scale * x @ A^T  (one wave per row) ----------------
__global__ __launch_bounds__(64) void k_lora_T(const float* __restrict__ x,
                                               const float* __restrict__ A,
                                               float* __restrict__ T) {
    const int m = blockIdx.x;
    const int lane = threadIdx.x;
    const float* xr = x + (long)m * DIN;
    float acc[RANK];
#pragma unroll
    for (int r = 0; r < RANK; ++r) acc[r] = 0.f;
    for (int k = lane * 4; k < DIN; k += 64 * 4) {
        f32x4 xv = *(const f32x4*)(xr + k);
#pragma unroll
        for (int r = 0; r < RANK; ++r) {
            f32x4 av = *(const f32x4*)(A + (long)r * DIN + k);
            acc[r] += xv[0] * av[0] + xv[1] * av[1] + xv[2] * av[2] + xv[3] * av[3];
        }
    }
#pragma unroll
    for (int r = 0; r < RANK; ++r)
        for (int off = 32; off > 0; off >>= 1) acc[r] += __shfl_down(acc[r], off);
    if (lane == 0) {
#pragma unroll
        for (int r = 0; r < RANK; ++r) T[(long)m * RANK + r] = acc[r] * LSCALE;
    }
}

// ---------------- fallback GEMM: f32 sources, reg-staged conversion ----------------
__global__ __launch_bounds__(256) void k_gemm_nows(const float* __restrict__ x,
                                                   const float* __restrict__ W,
                                                   const float* __restrict__ bias,
                                                   const float* __restrict__ T,
                                                   const float* __restrict__ lB,
                                                   float* __restrict__ out) {
    constexpr int FBM = 128, FBN = 128, FBK = 32, K = DIN, N = DOUT;
    __shared__ __align__(16) u16 As[FBM * FBK];
    __shared__ __align__(16) u16 Bs[FBN * FBK];

    const int tid = threadIdx.x;
    const int bm = blockIdx.y * FBM;
    const int bn = blockIdx.x * FBN;
    const int lane = tid & 63;
    const int wid  = tid >> 6;
    const int wr = wid >> 1, wc = wid & 1;
    const int lrow = lane & 15;
    const int kgrp = lane >> 4;

    const int c0 = tid, c1 = tid + 256;
    const float* aS0 = x + (long)(bm + (c0 >> 2)) * K + (c0 & 3) * 8;
    const float* aS1 = x + (long)(bm + (c1 >> 2)) * K + (c1 & 3) * 8;
    const float* bS0 = W + (long)(bn + (c0 >> 2)) * K + (c0 & 3) * 8;
    const float* bS1 = W + (long)(bn + (c1 >> 2)) * K + (c1 & 3) * 8;
    u16* aD0 = As + c0 * 8;  u16* aD1 = As + c1 * 8;
    u16* bD0 = Bs + c0 * 8;  u16* bD1 = Bs + c1 * 8;

    const u16* aR = As + (wr * 64 + lrow) * FBK + kgrp * 8;
    const u16* bR = Bs + (wc * 64 + lrow) * FBK + kgrp * 8;

    f32x4 acc[4][4];
#pragma unroll
    for (int i = 0; i < 4; ++i)
#pragma unroll
        for (int j = 0; j < 4; ++j) acc[i][j] = (f32x4){0.f, 0.f, 0.f, 0.f};

    for (int k0 = 0; k0 < K; k0 += FBK) {
        f32x4 a00 = *(const f32x4*)aS0, a01 = *(const f32x4*)(aS0 + 4);
        f32x4 a10 = *(const f32x4*)aS1, a11 = *(const f32x4*)(aS1 + 4);
        f32x4 b00 = *(const f32x4*)bS0, b01 = *(const f32x4*)(bS0 + 4);
        f32x4 b10 = *(const f32x4*)bS1, b11 = *(const f32x4*)(bS1 + 4);
        aS0 += FBK; aS1 += FBK; bS0 += FBK; bS1 += FBK;
        if (k0) __syncthreads();
        *(u16x8*)aD0 = pack8(a00, a01);
        *(u16x8*)aD1 = pack8(a10, a11);
        *(u16x8*)bD0 = pack8(b00, b01);
        *(u16x8*)bD1 = pack8(b10, b11);
        __syncthreads();

        bf16x8 af[4], bf[4];
#pragma unroll
        for (int i = 0; i < 4; ++i) af[i] = *(const bf16x8*)(aR + i * 16 * FBK);
#pragma unroll
        for (int j = 0; j < 4; ++j) bf[j] = *(const bf16x8*)(bR + j * 16 * FBK);
#pragma unroll
        for (int i = 0; i < 4; ++i)
#pragma unroll
            for (int j = 0; j < 4; ++j)
                acc[i][j] = __builtin_amdgcn_mfma_f32_16x16x32_bf16(af[i], bf[j], acc[i][j], 0, 0, 0);
    }

#pragma unroll
    for (int j = 0; j < 4; ++j) {
        const int col = bn + wc * 64 + j * 16 + lrow;
        const float bj = bias[col];
        float bl[RANK];
#pragma unroll
        for (int q = 0; q < RANK; ++q) bl[q] = lB[(long)col * RANK + q];
#pragma unroll
        for (int i = 0; i < 4; ++i) {
            const int row0 = bm + wr * 64 + i * 16 + kgrp * 4;
#pragma unroll
            for (int r = 0; r < 4; ++r) {
                const int row = row0 + r;
                const float* Trow = T + (long)row * RANK;
                float s = bj;
#pragma unroll
                for (int q = 0; q < RANK; ++q) s += Trow[q] * bl[q];
                out[(long)row * N + col] = acc[i][j][r] + s;
            }
        }
    }
}

extern "C" void kernel_launch(void* const* d_in, const int* in_sizes, int n_in,
                              void* d_out, int out_size, void* d_ws, size_t ws_size,
                              hipStream_t stream) {
    const float* x    = (const float*)d_in[0];
    const float* W    = (const float*)d_in[1];
    const float* bias = (const float*)d_in[2];
    const float* lA   = (const float*)d_in[3];
    const float* lB   = (const float*)d_in[4];
    float* out = (float*)d_out;

    const size_t xb_bytes = (size_t)MTOT * DIN * sizeof(u16);   // 64 MiB
    const size_t wb_bytes = (size_t)DOUT * DIN * sizeof(u16);   // 32 MiB

    if (ws_size >= xb_bytes + wb_bytes) {
        u16* xb = (u16*)d_ws;
        u16* wb = (u16*)((char*)d_ws + xb_bytes);
        k_convert_x <<<(int)((long)MTOT * DIN / 8 / 256), 256, 0, stream>>>(x, xb);
        k_build_weff<<<(DOUT / WEFF_OPG) * (DIN / 8) / 256, 256, 0, stream>>>(W, lA, lB, wb);
        k_gemm_ws   <<<(MTOT / BM) * (DOUT / BN), 256, 0, stream>>>(xb, wb, bias, out);
    } else {
        float* T = (float*)d_ws;   // 512 KiB
        k_lora_T   <<<MTOT, 64, 0, stream>>>(x, lA, T);
        k_gemm_nows<<<dim3(DOUT / 128, MTOT / 128), 256, 0, stream>>>(x, W, bias, T, lB, out);
    }
}

// Round 17
// 279.509 us; speedup vs baseline: 1.4521x; 1.4521x over previous
//
#include <hip/hip_runtime.h>
#include <stdint.h>

// ---------------- problem constants (from reference) ----------------
#define DIN   4096
#define DOUT  4096
#define RANK  16
#define MTOT  8192            // 4 * 2048
#define LSCALE 2.0f           // alpha/rank = 32/16

typedef unsigned short u16;
typedef __bf16 bf16x8 __attribute__((ext_vector_type(8)));
typedef float  f32x4  __attribute__((ext_vector_type(4)));
typedef u16    u16x8  __attribute__((ext_vector_type(8)));

__device__ __forceinline__ u16 f2bf(float f) {
    uint32_t u = __builtin_bit_cast(uint32_t, f);
    u = (u + 0x7FFFu + ((u >> 16) & 1u)) >> 16;   // RNE
    return (u16)u;
}

__device__ __forceinline__ u16x8 pack8(f32x4 a, f32x4 b) {
    u16x8 o;
    o[0] = f2bf(a[0]); o[1] = f2bf(a[1]); o[2] = f2bf(a[2]); o[3] = f2bf(a[3]);
    o[4] = f2bf(b[0]); o[5] = f2bf(b[1]); o[6] = f2bf(b[2]); o[7] = f2bf(b[3]);
    return o;
}

#define GLDS16(g, l) __builtin_amdgcn_global_load_lds( \
    (const __attribute__((address_space(1))) void*)(g), \
    (__attribute__((address_space(3))) void*)(l), 16, 0, 0)

// ---------------- pass 1a: x (f32) -> xb (bf16) ----------------
__global__ __launch_bounds__(256) void k_convert_x(const float* __restrict__ x,
                                                   u16* __restrict__ xb) {
    long i = ((long)blockIdx.x * 256 + threadIdx.x) * 8;
    f32x4 a = *(const f32x4*)(x + i);
    f32x4 b = *(const f32x4*)(x + i + 4);
    *(u16x8*)(xb + i) = pack8(a, b);
}

// ---------------- pass 1b: W_eff = W + scale * B @ A  (bf16) ----------------
// Thread owns one d-chunk (8 f32) and 16 consecutive o rows; A-chunks hoisted
// to registers once (A L2 traffic 1GB -> 64MB).  [r12: at memory floor]
#define WEFF_OPG 16
__global__ __launch_bounds__(256) void k_build_weff(const float* __restrict__ W,
                                                    const float* __restrict__ A,
                                                    const float* __restrict__ B,
                                                    u16* __restrict__ wb) {
    const long t = (long)blockIdx.x * 256 + threadIdx.x;   // 512 dchunks x 256 ogroups
    const int dc = (int)(t & 511);
    const int og = (int)(t >> 9);
    const int d  = dc * 8;
    f32x4 a0[RANK], a1[RANK];
#pragma unroll
    for (int r = 0; r < RANK; ++r) {
        a0[r] = *(const f32x4*)(A + (long)r * DIN + d);
        a1[r] = *(const f32x4*)(A + (long)r * DIN + d + 4);
    }
#pragma unroll 4
    for (int j = 0; j < WEFF_OPG; ++j) {
        const int o = og * WEFF_OPG + j;
        const long i = (long)o * DIN + d;
        f32x4 w0 = *(const f32x4*)(W + i);
        f32x4 w1 = *(const f32x4*)(W + i + 4);
#pragma unroll
        for (int r = 0; r < RANK; ++r) {
            const float s = B[o * RANK + r] * LSCALE;
            w0 += a0[r] * s;
            w1 += a1[r] * s;
        }
        *(u16x8*)(wb + i) = pack8(w0, w1);
    }
}

// ---------------- main GEMM: out = xb @ wb^T + bias ----------------
// r12 structure (session best: 244 us, MfmaUtil 51.5%), setprio REMOVED
// (T5 is null-to-negative on 2-phase GEMM structures — m190/m228d/m230).
// 256x256, BK=64, 8 waves (2Mx4N, wave 128x64), 16x16x32 MFMA, TWO phases
// (two barriers) per K-tile:
//   Ph1: stage A.lo+A.hi(t+1)->nxt; read afL(8)+bfHi(4); Q1=afL*bfLo,
//        Q2=afL*bfHi; BAR
//   Ph2: stage B.lo+B.hi(t+2)->cur; GATE vmcnt(4); read afH(8)+bfLo(t+1)(4);
//        Q3=afH*bfLo, Q4=afH*bfHi; BAR
// FIFO at Ph2 gate: outstanding = B(t+1)[4] + A(t+1)[4] + B(t+2)[4] = 12;
// vmcnt(4) retires B(t+1)+A(t+1) (read next phase), keeps B(t+2) in flight.
// Write-after-read: every stage target's last reads were consumed (lgkm)
// before the previous barrier -> 1-barrier gap suffices. vmcnt never 0.
#define BM 256
#define BN 256
#define BK 64
#define NT (DIN / BK)          // 64 K-tiles

#define MFMA16(d, a, b) d = __builtin_amdgcn_mfma_f32_16x16x32_bf16(a, b, d, 0, 0, 0)
#define ABAR()   asm volatile("s_barrier" ::: "memory")
#define GATE4()  asm volatile("s_waitcnt vmcnt(4)" ::: "memory")

// 16 MFMAs, kk-outer (8 independent accs between dependent reuses)
#define QUADK(mo, no, AF, BF) \
    _Pragma("unroll") \
    for (int kk = 0; kk < 2; ++kk) { \
        _Pragma("unroll") \
        for (int m = 0; m < 4; ++m) { \
            _Pragma("unroll") \
            for (int n = 0; n < 2; ++n) { \
                MFMA16(acc[(mo)+m][(no)+n], AF[m][kk], BF[n][kk]); \
            } \
        } \
    }

__global__ __launch_bounds__(512, 2) void k_gemm_ws(const u16* __restrict__ xb,
                                                    const u16* __restrict__ wb,
                                                    const float* __restrict__ bias,
                                                    float* __restrict__ out) {
    constexpr int K = DIN, N = DOUT;
    __shared__ alignas(16) u16 lds[65536];   // A0@0 A1@16384 B0@32768 B1@49152 (u16)

    // T1: bijective XCD swizzle (gridDim.x = 512, divisible by 8)
    const int nchunk = gridDim.x >> 3;
    const int bid = blockIdx.x;
    const int wg  = (bid & 7) * nchunk + (bid >> 3);
    const int bm  = (wg & 31) * BM;
    const int bn  = (wg >> 5) * BN;

    const int tid  = threadIdx.x;
    const int lane = tid & 63;
    const int wid  = tid >> 6;         // 0..7
    const int wr   = wid >> 2;         // 0..1 -> rows wr*128..+127
    const int wc   = wid & 3;          // 0..3 -> cols wc*64..+63
    const int lrow = lane & 15;
    const int kgrp = lane >> 4;        // 0..3

    // ---- staging geometry (T2: pre-swizzled global source, linear LDS dest) ----
    const int srow = tid >> 3;                       // 0..63
    const int sgl  = (tid & 7) ^ (srow & 7);
    const u16* const aSrcB = xb + (long)(bm + srow) * K + sgl * 8;
    const u16* const bSrcB = wb + (long)(bn + srow) * K + sgl * 8;

    // chunk c = tile rows 64c..64c+63. lo = c0,c1; hi = c2,c3.
#define STAGE_A(c, buf, kt) GLDS16(aSrcB + (long)(64*(c))*K + (kt)*BK, \
                                   lds + (buf)*16384 + (c)*4096 + tid*8)
#define STAGE_B(c, buf, kt) GLDS16(bSrcB + (long)(64*(c))*K + (kt)*BK, \
                                   lds + 32768 + (buf)*16384 + (c)*4096 + tid*8)

    // ---- fragment-read geometry (swizzled) ----
    const int go0 = (kgrp ^ (lrow & 7)) * 8;   // kk=0 granule (u16 units)
    const int go1 = go0 ^ 32;                  // kk=1 (granule ^ 4)
    const int arow = (wr*128 + lrow) * 64;     // wave A base row offset
    const int brow = (wc*64  + lrow) * 64;     // wave B base row offset

    const u16* const cA0 = lds +         arow;
    const u16* const cA1 = lds + 16384 + arow;
    const u16* const cB0 = lds + 32768 +         brow;
    const u16* const cB1 = lds + 32768 + 16384 + brow;

    f32x4 acc[8][4];
#pragma unroll
    for (int m = 0; m < 8; ++m)
#pragma unroll
        for (int n = 0; n < 4; ++n) acc[m][n] = (f32x4){0.f, 0.f, 0.f, 0.f};

    bf16x8 afL[4][2], afH[4][2], bfHi[2][2], bLoA[2][2], bLoB[2][2];

#define READ_AF(DST, BASE, OFS) \
    _Pragma("unroll") \
    for (int mf = 0; mf < 4; ++mf) { \
        const u16* b_ = (BASE) + ((OFS) + mf) * 1024; \
        DST[mf][0] = *(const bf16x8*)(b_ + go0); \
        DST[mf][1] = *(const bf16x8*)(b_ + go1); \
    }
#define READ_BF(DST, BASE, OFS) \
    _Pragma("unroll") \
    for (int nf = 0; nf < 2; ++nf) { \
        const u16* b_ = (BASE) + ((OFS) + nf) * 1024; \
        DST[nf][0] = *(const bf16x8*)(b_ + go0); \
        DST[nf][1] = *(const bf16x8*)(b_ + go1); \
    }

    // ---- prologue: A(0),B(0)->buf0; B(1)->buf1; counted gate; read bfLo(0) ----
    STAGE_A(0, 0, 0); STAGE_A(1, 0, 0);
    STAGE_A(2, 0, 0); STAGE_A(3, 0, 0);
    STAGE_B(0, 0, 0); STAGE_B(1, 0, 0);
    STAGE_B(2, 0, 0); STAGE_B(3, 0, 0);
    STAGE_B(0, 1, 1); STAGE_B(1, 1, 1);
    STAGE_B(2, 1, 1); STAGE_B(3, 1, 1);
    GATE4();                       // retires A(0)+B(0); keeps B(1) in flight
    __syncthreads();
    READ_BF(bLoA, cB0, 0);

    for (int it = 0; it < NT/2; ++it) {
        const int kt1 = 2*it + 1;              // <= 63
        const int kt2 = (2*it + 2) & (NT - 1); // wraps on last iter (unused)
        const int kt3 = (2*it + 3) & (NT - 1);

        // ================= even tile t=2it (A buf0, B buf0, bfLo=bLoA) ==========
        // Ph1: stage A(t+1)->buf1; read afL + bfHi; Q1,Q2
        STAGE_A(0, 1, kt1); STAGE_A(1, 1, kt1);
        STAGE_A(2, 1, kt1); STAGE_A(3, 1, kt1);
        READ_AF(afL, cA0, 0);
        READ_BF(bfHi, cB0, 2);
        QUADK(0, 0, afL, bLoA); QUADK(0, 2, afL, bfHi);
        ABAR();
        // Ph2: stage B(t+2)->buf0; GATE; read afH + bfLo(t+1); Q3,Q4
        STAGE_B(0, 0, kt2); STAGE_B(1, 0, kt2);
        STAGE_B(2, 0, kt2); STAGE_B(3, 0, kt2);
        GATE4();                               // retires A(t+1)+B(t+1)
        READ_AF(afH, cA0, 4);
        READ_BF(bLoB, cB1, 0);
        QUADK(4, 0, afH, bLoA); QUADK(4, 2, afH, bfHi);
        ABAR();

        // ================= odd tile t+1 (A buf1, B buf1, bfLo=bLoB) =============
        STAGE_A(0, 0, kt2); STAGE_A(1, 0, kt2);
        STAGE_A(2, 0, kt2); STAGE_A(3, 0, kt2);
        READ_AF(afL, cA1, 0);
        READ_BF(bfHi, cB1, 2);
        QUADK(0, 0, afL, bLoB); QUADK(0, 2, afL, bfHi);
        ABAR();

        STAGE_B(0, 1, kt3); STAGE_B(1, 1, kt3);
        STAGE_B(2, 1, kt3); STAGE_B(3, 1, kt3);
        GATE4();                               // retires A(t+2)+B(t+2)
        READ_AF(afH, cA1, 4);
        READ_BF(bLoA, cB0, 0);
        QUADK(4, 0, afH, bLoB); QUADK(4, 2, afH, bfHi);
        ABAR();
    }
    asm volatile("s_waitcnt vmcnt(0)" ::: "memory");   // drain wrapped prefetch

    // ---- epilogue: + bias, store f32 ----
    const int orow = bm + wr*128 + kgrp*4;
    const int ocol = bn + wc*64 + lrow;
#pragma unroll
    for (int n = 0; n < 4; ++n) {
        const int col = ocol + n*16;
        const float bj = bias[col];
#pragma unroll
        for (int m = 0; m < 8; ++m) {
            const int row = orow + m*16;
#pragma unroll
            for (int r = 0; r < 4; ++r)
                out[(long)(row + r) * N + col] = acc[m][n][r] + bj;
        }
    }
}

// ---------------- fallback: T = scale * x @ A^T  (one wave per row) ----------------
__global__ __launch_bounds__(64) void k_lora_T(const float* __restrict__ x,
                                               const float* __restrict__ A,
                                               float* __restrict__ T) {
    const int m = blockIdx.x;
    const int lane = threadIdx.x;
    const float* xr = x + (long)m * DIN;
    float acc[RANK];
#pragma unroll
    for (int r = 0; r < RANK; ++r) acc[r] = 0.f;
    for (int k = lane * 4; k < DIN; k += 64 * 4) {
        f32x4 xv = *(const f32x4*)(xr + k);
#pragma unroll
        for (int r = 0; r < RANK; ++r) {
            f32x4 av = *(const f32x4*)(A + (long)r * DIN + k);
            acc[r] += xv[0] * av[0] + xv[1] * av[1] + xv[2] * av[2] + xv[3] * av[3];
        }
    }
#pragma unroll
    for (int r = 0; r < RANK; ++r)
        for (int off = 32; off > 0; off >>= 1) acc[r] += __shfl_down(acc[r], off);
    if (lane == 0) {
#pragma unroll
        for (int r = 0; r < RANK; ++r) T[(long)m * RANK + r] = acc[r] * LSCALE;
    }
}

// ---------------- fallback GEMM: f32 sources, reg-staged conversion ----------------
__global__ __launch_bounds__(256) void k_gemm_nows(const float* __restrict__ x,
                                                   const float* __restrict__ W,
                                                   const float* __restrict__ bias,
                                                   const float* __restrict__ T,
                                                   const float* __restrict__ lB,
                                                   float* __restrict__ out) {
    constexpr int FBM = 128, FBN = 128, FBK = 32, K = DIN, N = DOUT;
    __shared__ __align__(16) u16 As[FBM * FBK];
    __shared__ __align__(16) u16 Bs[FBN * FBK];

    const int tid = threadIdx.x;
    const int bm = blockIdx.y * FBM;
    const int bn = blockIdx.x * FBN;
    const int lane = tid & 63;
    const int wid  = tid >> 6;
    const int wr = wid >> 1, wc = wid & 1;
    const int lrow = lane & 15;
    const int kgrp = lane >> 4;

    const int c0 = tid, c1 = tid + 256;
    const float* aS0 = x + (long)(bm + (c0 >> 2)) * K + (c0 & 3) * 8;
    const float* aS1 = x + (long)(bm + (c1 >> 2)) * K + (c1 & 3) * 8;
    const float* bS0 = W + (long)(bn + (c0 >> 2)) * K + (c0 & 3) * 8;
    const float* bS1 = W + (long)(bn + (c1 >> 2)) * K + (c1 & 3) * 8;
    u16* aD0 = As + c0 * 8;  u16* aD1 = As + c1 * 8;
    u16* bD0 = Bs + c0 * 8;  u16* bD1 = Bs + c1 * 8;

    const u16* aR = As + (wr * 64 + lrow) * FBK + kgrp * 8;
    const u16* bR = Bs + (wc * 64 + lrow) * FBK + kgrp * 8;

    f32x4 acc[4][4];
#pragma unroll
    for (int i = 0; i < 4; ++i)
#pragma unroll
        for (int j = 0; j < 4; ++j) acc[i][j] = (f32x4){0.f, 0.f, 0.f, 0.f};

    for (int k0 = 0; k0 < K; k0 += FBK) {
        f32x4 a00 = *(const f32x4*)aS0, a01 = *(const f32x4*)(aS0 + 4);
        f32x4 a10 = *(const f32x4*)aS1, a11 = *(const f32x4*)(aS1 + 4);
        f32x4 b00 = *(const f32x4*)bS0, b01 = *(const f32x4*)(bS0 + 4);
        f32x4 b10 = *(const f32x4*)bS1, b11 = *(const f32x4*)(bS1 + 4);
        aS0 += FBK; aS1 += FBK; bS0 += FBK; bS1 += FBK;
        if (k0) __syncthreads();
        *(u16x8*)aD0 = pack8(a00, a01);
        *(u16x8*)aD1 = pack8(a10, a11);
        *(u16x8*)bD0 = pack8(b00, b01);
        *(u16x8*)bD1 = pack8(b10, b11);
        __syncthreads();

        bf16x8 af[4], bf[4];
#pragma unroll
        for (int i = 0; i < 4; ++i) af[i] = *(const bf16x8*)(aR + i * 16 * FBK);
#pragma unroll
        for (int j = 0; j < 4; ++j) bf[j] = *(const bf16x8*)(bR + j * 16 * FBK);
#pragma unroll
        for (int i = 0; i < 4; ++i)
#pragma unroll
            for (int j = 0; j < 4; ++j)
                acc[i][j] = __builtin_amdgcn_mfma_f32_16x16x32_bf16(af[i], bf[j], acc[i][j], 0, 0, 0);
    }

#pragma unroll
    for (int j = 0; j < 4; ++j) {
        const int col = bn + wc * 64 + j * 16 + lrow;
        const float bj = bias[col];
        float bl[RANK];
#pragma unroll
        for (int q = 0; q < RANK; ++q) bl[q] = lB[(long)col * RANK + q];
#pragma unroll
        for (int i = 0; i < 4; ++i) {
            const int row0 = bm + wr * 64 + i * 16 + kgrp * 4;
#pragma unroll
            for (int r = 0; r < 4; ++r) {
                const int row = row0 + r;
                const float* Trow = T + (long)row * RANK;
                float s = bj;
#pragma unroll
                for (int q = 0; q < RANK; ++q) s += Trow[q] * bl[q];
                out[(long)row * N + col] = acc[i][j][r] + s;
            }
        }
    }
}

extern "C" void kernel_launch(void* const* d_in, const int* in_sizes, int n_in,
                              void* d_out, int out_size, void* d_ws, size_t ws_size,
                              hipStream_t stream) {
    const float* x    = (const float*)d_in[0];
    const float* W    = (const float*)d_in[1];
    const float* bias = (const float*)d_in[2];
    const float* lA   = (const float*)d_in[3];
    const float* lB   = (const float*)d_in[4];
    float* out = (float*)d_out;

    const size_t xb_bytes = (size_t)MTOT * DIN * sizeof(u16);   // 64 MiB
    const size_t wb_bytes = (size_t)DOUT * DIN * sizeof(u16);   // 32 MiB

    if (ws_size >= xb_bytes + wb_bytes) {
        u16* xb = (u16*)d_ws;
        u16* wb = (u16*)((char*)d_ws + xb_bytes);
        k_convert_x <<<(int)((long)MTOT * DIN / 8 / 256), 256, 0, stream>>>(x, xb);
        k_build_weff<<<(DOUT / WEFF_OPG) * (DIN / 8) / 256, 256, 0, stream>>>(W, lA, lB, wb);
        k_gemm_ws   <<<(MTOT / BM) * (DOUT / BN), 512, 0, stream>>>(xb, wb, bias, out);
    } else {
        float* T = (float*)d_ws;   // 512 KiB
        k_lora_T   <<<MTOT, 64, 0, stream>>>(x, lA, T);
        k_gemm_nows<<<dim3(DOUT / 128, MTOT / 128), 256, 0, stream>>>(x, W, bias, T, lB, out);
    }
}

// Round 18
// 278.187 us; speedup vs baseline: 1.4590x; 1.0048x over previous
//
#include <hip/hip_runtime.h>
#include <stdint.h>

// ---------------- problem constants (from reference) ----------------
#define DIN   4096
#define DOUT  4096
#define RANK  16
#define MTOT  8192            // 4 * 2048
#define LSCALE 2.0f           // alpha/rank = 32/16

typedef unsigned short u16;
typedef __bf16 bf16x8 __attribute__((ext_vector_type(8)));
typedef float  f32x4  __attribute__((ext_vector_type(4)));
typedef u16    u16x8  __attribute__((ext_vector_type(8)));

__device__ __forceinline__ u16 f2bf(float f) {
    uint32_t u = __builtin_bit_cast(uint32_t, f);
    u = (u + 0x7FFFu + ((u >> 16) & 1u)) >> 16;   // RNE
    return (u16)u;
}

__device__ __forceinline__ u16x8 pack8(f32x4 a, f32x4 b) {
    u16x8 o;
    o[0] = f2bf(a[0]); o[1] = f2bf(a[1]); o[2] = f2bf(a[2]); o[3] = f2bf(a[3]);
    o[4] = f2bf(b[0]); o[5] = f2bf(b[1]); o[6] = f2bf(b[2]); o[7] = f2bf(b[3]);
    return o;
}

#define GLDS16(g, l) __builtin_amdgcn_global_load_lds( \
    (const __attribute__((address_space(1))) void*)(g), \
    (__attribute__((address_space(3))) void*)(l), 16, 0, 0)

// ---------------- pass 1a: x (f32) -> xb (bf16) ----------------
__global__ __launch_bounds__(256) void k_convert_x(const float* __restrict__ x,
                                                   u16* __restrict__ xb) {
    long i = ((long)blockIdx.x * 256 + threadIdx.x) * 8;
    f32x4 a = *(const f32x4*)(x + i);
    f32x4 b = *(const f32x4*)(x + i + 4);
    *(u16x8*)(xb + i) = pack8(a, b);
}

// ---------------- pass 1b: W_eff = W + scale * B @ A  (bf16) ----------------
// Thread owns one d-chunk (8 f32) and 16 consecutive o rows; A-chunks hoisted
// to registers once (A L2 traffic 1GB -> 64MB).  [r12: at memory floor]
#define WEFF_OPG 16
__global__ __launch_bounds__(256) void k_build_weff(const float* __restrict__ W,
                                                    const float* __restrict__ A,
                                                    const float* __restrict__ B,
                                                    u16* __restrict__ wb) {
    const long t = (long)blockIdx.x * 256 + threadIdx.x;   // 512 dchunks x 256 ogroups
    const int dc = (int)(t & 511);
    const int og = (int)(t >> 9);
    const int d  = dc * 8;
    f32x4 a0[RANK], a1[RANK];
#pragma unroll
    for (int r = 0; r < RANK; ++r) {
        a0[r] = *(const f32x4*)(A + (long)r * DIN + d);
        a1[r] = *(const f32x4*)(A + (long)r * DIN + d + 4);
    }
#pragma unroll 4
    for (int j = 0; j < WEFF_OPG; ++j) {
        const int o = og * WEFF_OPG + j;
        const long i = (long)o * DIN + d;
        f32x4 w0 = *(const f32x4*)(W + i);
        f32x4 w1 = *(const f32x4*)(W + i + 4);
#pragma unroll
        for (int r = 0; r < RANK; ++r) {
            const float s = B[o * RANK + r] * LSCALE;
            w0 += a0[r] * s;
            w1 += a1[r] * s;
        }
        *(u16x8*)(wb + i) = pack8(w0, w1);
    }
}

// ---------------- main GEMM: out = xb @ wb^T + bias ----------------
// r15 1-barrier schedule WITHOUT setprio (r17 finding: setprio builtins pin
// the MFMA cluster against scheduler interleave; removing them gave +7%).
// One barrier + one counted gate per K-tile maximizes the unpinned window:
// the scheduler can interleave 24 ds_reads with 64 MFMAs across the tile.
// 256x256, BK=64, 8 waves (2Mx4N, wave 128x64), 16x16x32 MFMA.
// Per tile t (parity p):
//   stage A(t+1)->A[p^1] (4); stage B(t+2)->B[p] (4)   [tile start]
//   read afL (8); 32 MFMA (B-set p regs)
//   read afH (8); 32 MFMA
//   GATE vmcnt(4)  [outstanding B(t+1)4 + A(t+1)4 + B(t+2)4 = 12 ->
//                   retires B(t+1) (read next) + A(t+1) (read after BAR);
//                   keeps B(t+2) in flight; never 0]
//   read B(t+1) frags from B[p^1]; ABAR
// Write-after-read: A[p^1]/B[p] targets last read during t-1, lgkm-consumed
// before the t-1/t barrier -> 1-barrier gap suffices.  [verified r15]
#define BM 256
#define BN 256
#define BK 64
#define NT (DIN / BK)          // 64 K-tiles

#define MFMA16(d, a, b) d = __builtin_amdgcn_mfma_f32_16x16x32_bf16(a, b, d, 0, 0, 0)
#define ABAR()   asm volatile("s_barrier" ::: "memory")
#define GATE4()  asm volatile("s_waitcnt vmcnt(4)" ::: "memory")

// 16 MFMAs, kk-outer (8 independent accs between dependent reuses)
#define QUADK(mo, no, AF, BF) \
    _Pragma("unroll") \
    for (int kk = 0; kk < 2; ++kk) { \
        _Pragma("unroll") \
        for (int m = 0; m < 4; ++m) { \
            _Pragma("unroll") \
            for (int n = 0; n < 2; ++n) { \
                MFMA16(acc[(mo)+m][(no)+n], AF[m][kk], BF[n][kk]); \
            } \
        } \
    }

__global__ __launch_bounds__(512, 2) void k_gemm_ws(const u16* __restrict__ xb,
                                                    const u16* __restrict__ wb,
                                                    const float* __restrict__ bias,
                                                    float* __restrict__ out) {
    constexpr int K = DIN, N = DOUT;
    __shared__ alignas(16) u16 lds[65536];   // A0@0 A1@16384 B0@32768 B1@49152 (u16)

    // T1: bijective XCD swizzle (gridDim.x = 512, divisible by 8)
    const int nchunk = gridDim.x >> 3;
    const int bid = blockIdx.x;
    const int wg  = (bid & 7) * nchunk + (bid >> 3);
    const int bm  = (wg & 31) * BM;
    const int bn  = (wg >> 5) * BN;

    const int tid  = threadIdx.x;
    const int lane = tid & 63;
    const int wid  = tid >> 6;         // 0..7
    const int wr   = wid >> 2;         // 0..1 -> rows wr*128..+127
    const int wc   = wid & 3;          // 0..3 -> cols wc*64..+63
    const int lrow = lane & 15;
    const int kgrp = lane >> 4;        // 0..3

    // ---- staging geometry (T2: pre-swizzled global source, linear LDS dest) ----
    const int srow = tid >> 3;                       // 0..63
    const int sgl  = (tid & 7) ^ (srow & 7);
    const u16* const aSrcB = xb + (long)(bm + srow) * K + sgl * 8;
    const u16* const bSrcB = wb + (long)(bn + srow) * K + sgl * 8;

    // chunk c = tile rows 64c..64c+63.
#define STAGE_A(c, buf, kt) GLDS16(aSrcB + (long)(64*(c))*K + (kt)*BK, \
                                   lds + (buf)*16384 + (c)*4096 + tid*8)
#define STAGE_B(c, buf, kt) GLDS16(bSrcB + (long)(64*(c))*K + (kt)*BK, \
                                   lds + 32768 + (buf)*16384 + (c)*4096 + tid*8)

    // ---- fragment-read geometry (swizzled) ----
    const int go0 = (kgrp ^ (lrow & 7)) * 8;   // kk=0 granule (u16 units)
    const int go1 = go0 ^ 32;                  // kk=1 (granule ^ 4)
    const int arow = (wr*128 + lrow) * 64;     // wave A base row offset
    const int brow = (wc*64  + lrow) * 64;     // wave B base row offset

    const u16* const cA0 = lds +         arow;
    const u16* const cA1 = lds + 16384 + arow;
    const u16* const cB0 = lds + 32768 +         brow;
    const u16* const cB1 = lds + 32768 + 16384 + brow;

    f32x4 acc[8][4];
#pragma unroll
    for (int m = 0; m < 8; ++m)
#pragma unroll
        for (int n = 0; n < 4; ++n) acc[m][n] = (f32x4){0.f, 0.f, 0.f, 0.f};

    bf16x8 afL[4][2], afH[4][2], bLoE[2][2], bHiE[2][2], bLoO[2][2], bHiO[2][2];

#define READ_AF(DST, BASE, OFS) \
    _Pragma("unroll") \
    for (int mf = 0; mf < 4; ++mf) { \
        const u16* b_ = (BASE) + ((OFS) + mf) * 1024; \
        DST[mf][0] = *(const bf16x8*)(b_ + go0); \
        DST[mf][1] = *(const bf16x8*)(b_ + go1); \
    }
#define READ_BF(DST, BASE, OFS) \
    _Pragma("unroll") \
    for (int nf = 0; nf < 2; ++nf) { \
        const u16* b_ = (BASE) + ((OFS) + nf) * 1024; \
        DST[nf][0] = *(const bf16x8*)(b_ + go0); \
        DST[nf][1] = *(const bf16x8*)(b_ + go1); \
    }

    // ---- prologue: A(0)->A0, B(0)->B0, B(1)->B1; gate; read B(0) frags ----
    STAGE_A(0, 0, 0); STAGE_A(1, 0, 0);
    STAGE_A(2, 0, 0); STAGE_A(3, 0, 0);
    STAGE_B(0, 0, 0); STAGE_B(1, 0, 0);
    STAGE_B(2, 0, 0); STAGE_B(3, 0, 0);
    STAGE_B(0, 1, 1); STAGE_B(1, 1, 1);
    STAGE_B(2, 1, 1); STAGE_B(3, 1, 1);
    GATE4();                       // retires A(0)+B(0); keeps B(1) in flight
    __syncthreads();
    READ_BF(bLoE, cB0, 0);
    READ_BF(bHiE, cB0, 2);

    for (int it = 0; it < NT/2; ++it) {
        const int kt1 = 2*it + 1;              // <= 63
        const int kt2 = (2*it + 2) & (NT - 1); // wraps on last iter (unused)
        const int kt3 = (2*it + 3) & (NT - 1);

        // ========== even tile t=2it (p=0): A in A0, B-set E ==========
        STAGE_A(0, 1, kt1); STAGE_A(1, 1, kt1);
        STAGE_A(2, 1, kt1); STAGE_A(3, 1, kt1);   // A(t+1)->A1
        STAGE_B(0, 0, kt2); STAGE_B(1, 0, kt2);
        STAGE_B(2, 0, kt2); STAGE_B(3, 0, kt2);   // B(t+2)->B0
        READ_AF(afL, cA0, 0);
        QUADK(0, 0, afL, bLoE); QUADK(0, 2, afL, bHiE);
        READ_AF(afH, cA0, 4);
        QUADK(4, 0, afH, bLoE); QUADK(4, 2, afH, bHiE);
        GATE4();                               // retires B(t+1)+A(t+1)
        READ_BF(bLoO, cB1, 0);                 // B(t+1) frags
        READ_BF(bHiO, cB1, 2);
        ABAR();

        // ========== odd tile t+1 (p=1): A in A1, B-set O ==========
        STAGE_A(0, 0, kt2); STAGE_A(1, 0, kt2);
        STAGE_A(2, 0, kt2); STAGE_A(3, 0, kt2);   // A(t+2)->A0
        STAGE_B(0, 1, kt3); STAGE_B(1, 1, kt3);
        STAGE_B(2, 1, kt3); STAGE_B(3, 1, kt3);   // B(t+3)->B1
        READ_AF(afL, cA1, 0);
        QUADK(0, 0, afL, bLoO); QUADK(0, 2, afL, bHiO);
        READ_AF(afH, cA1, 4);
        QUADK(4, 0, afH, bLoO); QUADK(4, 2, afH, bHiO);
        GATE4();                               // retires B(t+2)+A(t+2)
        READ_BF(bLoE, cB0, 0);                 // B(t+2) frags
        READ_BF(bHiE, cB0, 2);
        ABAR();
    }
    asm volatile("s_waitcnt vmcnt(0)" ::: "memory");   // drain wrapped prefetch

    // ---- epilogue: + bias, store f32 ----
    const int orow = bm + wr*128 + kgrp*4;
    const int ocol = bn + wc*64 + lrow;
#pragma unroll
    for (int n = 0; n < 4; ++n) {
        const int col = ocol + n*16;
        const float bj = bias[col];
#pragma unroll
        for (int m = 0; m < 8; ++m) {
            const int row = orow + m*16;
#pragma unroll
            for (int r = 0; r < 4; ++r)
                out[(long)(row + r) * N + col] = acc[m][n][r] + bj;
        }
    }
}

// ---------------- fallback: T = scale * x @ A^T  (one wave per row) ----------------
__global__ __launch_bounds__(64) void k_lora_T(const float* __restrict__ x,
                                               const float* __restrict__ A,
                                               float* __restrict__ T) {
    const int m = blockIdx.x;
    const int lane = threadIdx.x;
    const float* xr = x + (long)m * DIN;
    float acc[RANK];
#pragma unroll
    for (int r = 0; r < RANK; ++r) acc[r] = 0.f;
    for (int k = lane * 4; k < DIN; k += 64 * 4) {
        f32x4 xv = *(const f32x4*)(xr + k);
#pragma unroll
        for (int r = 0; r < RANK; ++r) {
            f32x4 av = *(const f32x4*)(A + (long)r * DIN + k);
            acc[r] += xv[0] * av[0] + xv[1] * av[1] + xv[2] * av[2] + xv[3] * av[3];
        }
    }
#pragma unroll
    for (int r = 0; r < RANK; ++r)
        for (int off = 32; off > 0; off >>= 1) acc[r] += __shfl_down(acc[r], off);
    if (lane == 0) {
#pragma unroll
        for (int r = 0; r < RANK; ++r) T[(long)m * RANK + r] = acc[r] * LSCALE;
    }
}

// ---------------- fallback GEMM: f32 sources, reg-staged conversion ----------------
__global__ __launch_bounds__(256) void k_gemm_nows(const float* __restrict__ x,
                                                   const float* __restrict__ W,
                                                   const float* __restrict__ bias,
                                                   const float* __restrict__ T,
                                                   const float* __restrict__ lB,
                                                   float* __restrict__ out) {
    constexpr int FBM = 128, FBN = 128, FBK = 32, K = DIN, N = DOUT;
    __shared__ __align__(16) u16 As[FBM * FBK];
    __shared__ __align__(16) u16 Bs[FBN * FBK];

    const int tid = threadIdx.x;
    const int bm = blockIdx.y * FBM;
    const int bn = blockIdx.x * FBN;
    const int lane = tid & 63;
    const int wid  = tid >> 6;
    const int wr = wid >> 1, wc = wid & 1;
    const int lrow = lane & 15;
    const int kgrp = lane >> 4;

    const int c0 = tid, c1 = tid + 256;
    const float* aS0 = x + (long)(bm + (c0 >> 2)) * K + (c0 & 3) * 8;
    const float* aS1 = x + (long)(bm + (c1 >> 2)) * K + (c1 & 3) * 8;
    const float* bS0 = W + (long)(bn + (c0 >> 2)) * K + (c0 & 3) * 8;
    const float* bS1 = W + (long)(bn + (c1 >> 2)) * K + (c1 & 3) * 8;
    u16* aD0 = As + c0 * 8;  u16* aD1 = As + c1 * 8;
    u16* bD0 = Bs + c0 * 8;  u16* bD1 = Bs + c1 * 8;

    const u16* aR = As + (wr * 64 + lrow) * FBK + kgrp * 8;
    const u16* bR = Bs + (wc * 64 + lrow) * FBK + kgrp * 8;

    f32x4 acc[4][4];
#pragma unroll
    for (int i = 0; i < 4; ++i)
#pragma unroll
        for (int j = 0; j < 4; ++j) acc[i][j] = (f32x4){0.f, 0.f, 0.f, 0.f};

    for (int k0 = 0; k0 < K; k0 += FBK) {
        f32x4 a00 = *(const f32x4*)aS0, a01 = *(const f32x4*)(aS0 + 4);
        f32x4 a10 = *(const f32x4*)aS1, a11 = *(const f32x4*)(aS1 + 4);
        f32x4 b00 = *(const f32x4*)bS0, b01 = *(const f32x4*)(bS0 + 4);
        f32x4 b10 = *(const f32x4*)bS1, b11 = *(const f32x4*)(bS1 + 4);
        aS0 += FBK; aS1 += FBK; bS0 += FBK; bS1 += FBK;
        if (k0) __syncthreads();
        *(u16x8*)aD0 = pack8(a00, a01);
        *(u16x8*)aD1 = pack8(a10, a11);
        *(u16x8*)bD0 = pack8(b00, b01);
        *(u16x8*)bD1 = pack8(b10, b11);
        __syncthreads();

        bf16x8 af[4], bf[4];
#pragma unroll
        for (int i = 0; i < 4; ++i) af[i] = *(const bf16x8*)(aR + i * 16 * FBK);
#pragma unroll
        for (int j = 0; j < 4; ++j) bf[j] = *(const bf16x8*)(bR + j * 16 * FBK);
#pragma unroll
        for (int i = 0; i < 4; ++i)
#pragma unroll
            for (int j = 0; j < 4; ++j)
                acc[i][j] = __builtin_amdgcn_mfma_f32_16x16x32_bf16(af[i], bf[j], acc[i][j], 0, 0, 0);
    }

#pragma unroll
    for (int j = 0; j < 4; ++j) {
        const int col = bn + wc * 64 + j * 16 + lrow;
        const float bj = bias[col];
        float bl[RANK];
#pragma unroll
        for (int q = 0; q < RANK; ++q) bl[q] = lB[(long)col * RANK + q];
#pragma unroll
        for (int i = 0; i < 4; ++i) {
            const int row0 = bm + wr * 64 + i * 16 + kgrp * 4;
#pragma unroll
            for (int r = 0; r < 4; ++r) {
                const int row = row0 + r;
                const float* Trow = T + (long)row * RANK;
                float s = bj;
#pragma unroll
                for (int q = 0; q < RANK; ++q) s += Trow[q] * bl[q];
                out[(long)row * N + col] = acc[i][j][r] + s;
            }
        }
    }
}

extern "C" void kernel_launch(void* const* d_in, const int* in_sizes, int n_in,
                              void* d_out, int out_size, void* d_ws, size_t ws_size,
                              hipStream_t stream) {
    const float* x    = (const float*)d_in[0];
    const float* W    = (const float*)d_in[1];
    const float* bias = (const float*)d_in[2];
    const float* lA   = (const float*)d_in[3];
    const float* lB   = (const float*)d_in[4];
    float* out = (float*)d_out;

    const size_t xb_bytes = (size_t)MTOT * DIN * sizeof(u16);   // 64 MiB
    const size_t wb_bytes = (size_t)DOUT * DIN * sizeof(u16);   // 32 MiB

    if (ws_size >= xb_bytes + wb_bytes) {
        u16* xb = (u16*)d_ws;
        u16* wb = (u16*)((char*)d_ws + xb_bytes);
        k_convert_x <<<(int)((long)MTOT * DIN / 8 / 256), 256, 0, stream>>>(x, xb);
        k_build_weff<<<(DOUT / WEFF_OPG) * (DIN / 8) / 256, 256, 0, stream>>>(W, lA, lB, wb);
        k_gemm_ws   <<<(MTOT / BM) * (DOUT / BN), 512, 0, stream>>>(xb, wb, bias, out);
    } else {
        float* T = (float*)d_ws;   // 512 KiB
        k_lora_T   <<<MTOT, 64, 0, stream>>>(x, lA, T);
        k_gemm_nows<<<dim3(DOUT / 128, MTOT / 128), 256, 0, stream>>>(x, W, bias, T, lB, out);
    }
}